// Round 5
// baseline (592.135 us; speedup 1.0000x reference)
//
#include <hip/hip_runtime.h>
#include <hip/hip_bf16.h>

typedef __bf16 bf16_t;
typedef bf16_t bf16x8 __attribute__((ext_vector_type(8)));
typedef bf16_t bf16x4 __attribute__((ext_vector_type(4)));
typedef float f32x4 __attribute__((ext_vector_type(4)));

#define N_TOK 4096
#define DIM   768
#define HID   3072
#define NEXP  8
#define PADROWS 9216   // 8192 + 8*128 headroom for per-expert 128-padding

// ---------------- ws layout (bytes) ----------------
#define OFF_COUNTS 0
#define OFF_PSUM   32
#define OFF_OFFPAD 64      // int off_pad[9]
#define OFF_CURSOR 128
#define OFF_TOKE   256                         // int[8192]
#define OFF_TOKW   (OFF_TOKE + 4*8192)         // float[8192]
#define OFF_PERMT  (OFF_TOKW + 4*8192)         // int[PADROWS]
#define OFF_PERMW  (OFF_PERMT + 4*PADROWS)     // float[PADROWS]
#define OFF_XP     (((OFF_PERMW + 4*PADROWS) + 511) & ~511ull)  // bf16[PADROWS*DIM]
#define OFF_WFC    (OFF_XP + 2ull*PADROWS*DIM)                  // bf16[8*HID*DIM]
#define OFF_WPJ    (OFF_WFC + 2ull*NEXP*HID*DIM)                // bf16[8*DIM*HID]
#define OFF_H      (OFF_WPJ + 2ull*NEXP*DIM*HID)                // bf16[PADROWS*HID]
#define WS_NEEDED  (OFF_H + 2ull*PADROWS*HID)

// ---------------- async global->LDS 16B ----------------
__device__ __forceinline__ void async_copy16(const bf16_t* g, bf16_t* l) {
    __builtin_amdgcn_global_load_lds(
        (const __attribute__((address_space(1))) void*)g,
        (__attribute__((address_space(3))) void*)l, 16, 0, 0);
}

// ---------------- gating: one wave per token ----------------
__global__ __launch_bounds__(256) void gate_kernel(
    const float* __restrict__ x, const float* __restrict__ gw,
    int* __restrict__ counts, float* __restrict__ probs_sum,
    int* __restrict__ tok_e, float* __restrict__ tok_w)
{
    __shared__ float ps[8];
    __shared__ int cs[8];
    if (threadIdx.x < 8) { ps[threadIdx.x] = 0.f; cs[threadIdx.x] = 0; }
    __syncthreads();

    const int wv = threadIdx.x >> 6, lane = threadIdx.x & 63;
    const int n = blockIdx.x * 4 + wv;

    float acc[8];
#pragma unroll
    for (int e = 0; e < 8; e++) acc[e] = 0.f;
    const float* xr = x + (size_t)n * DIM;
#pragma unroll
    for (int c = 0; c < 12; c++) {
        const float xv = xr[c * 64 + lane];
#pragma unroll
        for (int e = 0; e < 8; e++) acc[e] += xv * gw[e * DIM + c * 64 + lane];
    }
#pragma unroll
    for (int e = 0; e < 8; e++)
        for (int off = 32; off > 0; off >>= 1) acc[e] += __shfl_xor(acc[e], off, 64);

    float mx = acc[0];
#pragma unroll
    for (int e = 1; e < 8; e++) mx = fmaxf(mx, acc[e]);
    float p[8], s = 0.f;
#pragma unroll
    for (int e = 0; e < 8; e++) { p[e] = expf(acc[e] - mx); s += p[e]; }

    int e1 = 0;
#pragma unroll
    for (int e = 1; e < 8; e++) if (p[e] > p[e1]) e1 = e;
    int e2 = (e1 == 0) ? 1 : 0;
#pragma unroll
    for (int e = 0; e < 8; e++) if (e != e1 && p[e] > p[e2]) e2 = e;
    const float denom = p[e1] + p[e2];

    if (lane == 0) {
        tok_e[2 * n] = e1; tok_e[2 * n + 1] = e2;
        tok_w[2 * n] = p[e1] / denom; tok_w[2 * n + 1] = p[e2] / denom;
        const float inv = 1.f / s;
#pragma unroll
        for (int e = 0; e < 8; e++) atomicAdd(&ps[e], p[e] * inv);
        atomicAdd(&cs[e1], 1); atomicAdd(&cs[e2], 1);
    }
    __syncthreads();
    if (threadIdx.x < 8) {
        atomicAdd(&probs_sum[threadIdx.x], ps[threadIdx.x]);
        atomicAdd(&counts[threadIdx.x], cs[threadIdx.x]);
    }
}

// ---------------- finalize: padded offsets + balance loss ----------------
__global__ void finalize_gate(const int* __restrict__ counts,
                              const float* __restrict__ probs_sum,
                              int* __restrict__ off_pad, int* __restrict__ cursor,
                              float* __restrict__ out_loss)
{
    if (threadIdx.x == 0) {
        int off = 0;
        for (int e = 0; e < 8; e++) {
            off_pad[e] = off; cursor[e] = off;
            off += ((counts[e] + 127) & ~127);
        }
        off_pad[8] = off;
        float loss = 0.f;
        for (int e = 0; e < 8; e++) loss += probs_sum[e] * (float)counts[e];
        loss *= 8.f / ((float)N_TOK * (float)N_TOK);
        *out_loss = loss;
    }
}

// ---------------- scatter tokens into padded per-expert segments ----------------
__global__ __launch_bounds__(256) void scatter_kernel(
    const int* __restrict__ tok_e, const float* __restrict__ tok_w,
    int* __restrict__ cursor, int* __restrict__ perm_tok, float* __restrict__ perm_w)
{
    const int n = blockIdx.x * 256 + threadIdx.x;
    if (n < N_TOK) {
#pragma unroll
        for (int k = 0; k < 2; k++) {
            const int e = tok_e[2 * n + k];
            const int pos = atomicAdd(&cursor[e], 1);
            perm_tok[pos] = n;
            perm_w[pos] = tok_w[2 * n + k];
        }
    }
}

// ---------------- convert both weight tensors fp32 -> bf16 ----------------
__global__ __launch_bounds__(256) void convert_w_kernel(
    const float* __restrict__ w_fc, const float* __restrict__ w_proj,
    bf16_t* __restrict__ wfc_b, bf16_t* __restrict__ wpj_b)
{
    const long long half = 18874368LL;  // 8*3072*768
    long long base = ((long long)blockIdx.x * 256 + threadIdx.x) * 16;
    const float* src; bf16_t* dst;
    if (base < half) { src = w_fc + base; dst = wfc_b + base; }
    else             { src = w_proj + (base - half); dst = wpj_b + (base - half); }
    float v[16];
    *(float4*)&v[0]  = *(const float4*)(src);
    *(float4*)&v[4]  = *(const float4*)(src + 4);
    *(float4*)&v[8]  = *(const float4*)(src + 8);
    *(float4*)&v[12] = *(const float4*)(src + 12);
    bf16x8 lo, hi;
#pragma unroll
    for (int i = 0; i < 8; i++) { lo[i] = (bf16_t)v[i]; hi[i] = (bf16_t)v[8 + i]; }
    *(bf16x8*)dst       = lo;
    *(bf16x8*)(dst + 8) = hi;
}

// ---------------- gather permuted tokens, fp32 -> bf16, zero pad rows ----------------
__global__ __launch_bounds__(256) void gather_x_kernel(
    const float* __restrict__ x, const int* __restrict__ off_pad,
    const int* __restrict__ counts, const int* __restrict__ perm_tok,
    bf16_t* __restrict__ xp)
{
    __shared__ int so[9], scnt[8];
    if (threadIdx.x < 9) so[threadIdx.x] = off_pad[threadIdx.x];
    if (threadIdx.x < 8) scnt[threadIdx.x] = counts[threadIdx.x];
    __syncthreads();
    const int gid = blockIdx.x * 256 + threadIdx.x;
    const int p = gid / 192;            // padded row
    const int c = (gid - p * 192) * 4;  // column
    int e = 0;
#pragma unroll
    for (int k = 1; k < 8; k++) if (p >= so[k]) e = k;
    const bool valid = (p < so[8]) && (p - so[e] < scnt[e]);
    float4 v = make_float4(0.f, 0.f, 0.f, 0.f);
    if (valid) {
        const int tok = perm_tok[p];
        v = *(const float4*)(x + (size_t)tok * DIM + c);
    }
    bf16x4 o; o[0] = (bf16_t)v.x; o[1] = (bf16_t)v.y; o[2] = (bf16_t)v.z; o[3] = (bf16_t)v.w;
    *(bf16x4*)(xp + (size_t)p * DIM + c) = o;
}

// ---------------- GEMM1: h = relu(xp @ w_fc^T)^2 ----------------
// 128x128 tile, BK=64, XOR-swizzled LDS, single-buffer K-loop (R3 structure).
__global__ __launch_bounds__(256, 2) void gemm1_kernel(
    const bf16_t* __restrict__ xp, const bf16_t* __restrict__ wfc,
    const int* __restrict__ off_pad, bf16_t* __restrict__ h)
{
    const int e = blockIdx.z;
    const int seg0 = off_pad[e];
    const int cnt_pad = off_pad[e + 1] - seg0;
    const int m0 = blockIdx.x * 128;
    if (m0 >= cnt_pad) return;
    const int n0 = blockIdx.y * 128;  // over HID

    __shared__ bf16_t As[128 * 64];
    __shared__ bf16_t Bs[128 * 64];

    const int t = threadIdx.x;
    const int srow = t >> 3, sc = t & 7;
    const int gsc = sc ^ (srow & 7);   // swizzled global chunk -> linear LDS slot
    const bf16_t* abase = xp + (size_t)(seg0 + m0 + srow) * DIM + gsc * 8;
    const bf16_t* bbase = wfc + ((size_t)e * HID + n0 + srow) * DIM + gsc * 8;

    const int wv = t >> 6, lane = t & 63;
    const int lrow = lane & 15, quad = lane >> 4;
    const int wm = (wv & 1) * 64, wn = (wv >> 1) * 64;
    const int sw = lrow & 7;           // read-side swizzle key

    f32x4 acc[4][4] = {};

    for (int k0 = 0; k0 < DIM; k0 += 64) {
        __syncthreads();
#pragma unroll
        for (int ii = 0; ii < 4; ii++) {
            async_copy16(abase + (size_t)ii * 32 * DIM + k0, &As[(ii * 256 + t) * 8]);
            async_copy16(bbase + (size_t)ii * 32 * DIM + k0, &Bs[(ii * 256 + t) * 8]);
        }
        __syncthreads();
#pragma unroll
        for (int kh = 0; kh < 2; kh++) {
            const int ch = ((kh * 4 + quad) ^ sw) * 8;
            bf16x8 af[4], bfv[4];
#pragma unroll
            for (int i = 0; i < 4; i++)
                af[i] = *(bf16x8*)&As[(wm + i * 16 + lrow) * 64 + ch];
#pragma unroll
            for (int j = 0; j < 4; j++)
                bfv[j] = *(bf16x8*)&Bs[(wn + j * 16 + lrow) * 64 + ch];
#pragma unroll
            for (int i = 0; i < 4; i++)
#pragma unroll
                for (int j = 0; j < 4; j++)
                    acc[i][j] = __builtin_amdgcn_mfma_f32_16x16x32_bf16(af[i], bfv[j], acc[i][j], 0, 0, 0);
        }
    }

    // epilogue: relu^2 -> bf16. C/D map: col=lane&15 (n), row=quad*4+reg (m).
#pragma unroll
    for (int i = 0; i < 4; i++) {
#pragma unroll
        for (int g = 0; g < 4; g++) {
            const int m = m0 + wm + i * 16 + quad * 4 + g;
            bf16_t* hrow = h + (size_t)(seg0 + m) * HID + n0 + wn + lrow;
#pragma unroll
            for (int j = 0; j < 4; j++) {
                float v = fmaxf(acc[i][j][g], 0.f);
                hrow[j * 16] = (bf16_t)(v * v);
            }
        }
    }
}

// ---------------- GEMM2: out[tok] += w * (h @ w_proj^T), split-K=4, atomics ----------------
__global__ __launch_bounds__(256, 2) void gemm2_kernel(
    const bf16_t* __restrict__ h, const bf16_t* __restrict__ wpj,
    const int* __restrict__ off_pad, const int* __restrict__ counts,
    const int* __restrict__ perm_tok, const float* __restrict__ perm_w,
    float* __restrict__ out)
{
    const int e = blockIdx.z >> 2, split = blockIdx.z & 3;
    const int seg0 = off_pad[e];
    const int cnt = counts[e];
    const int m0 = blockIdx.x * 128;
    if (m0 >= cnt) return;
    const int n0 = blockIdx.y * 128;  // over DIM
    const int kbeg = split * (HID / 4);

    __shared__ bf16_t As[128 * 64];
    __shared__ bf16_t Bs[128 * 64];

    const int t = threadIdx.x;
    const int srow = t >> 3, sc = t & 7;
    const int gsc = sc ^ (srow & 7);
    const bf16_t* abase = h + (size_t)(seg0 + m0 + srow) * HID + kbeg + gsc * 8;
    const bf16_t* bbase = wpj + ((size_t)e * DIM + n0 + srow) * HID + kbeg + gsc * 8;

    const int wv = t >> 6, lane = t & 63;
    const int lrow = lane & 15, quad = lane >> 4;
    const int wm = (wv & 1) * 64, wn = (wv >> 1) * 64;
    const int sw = lrow & 7;

    f32x4 acc[4][4] = {};

    for (int k0 = 0; k0 < HID / 4; k0 += 64) {
        __syncthreads();
#pragma unroll
        for (int ii = 0; ii < 4; ii++) {
            async_copy16(abase + (size_t)ii * 32 * HID + k0, &As[(ii * 256 + t) * 8]);
            async_copy16(bbase + (size_t)ii * 32 * HID + k0, &Bs[(ii * 256 + t) * 8]);
        }
        __syncthreads();
#pragma unroll
        for (int kh = 0; kh < 2; kh++) {
            const int ch = ((kh * 4 + quad) ^ sw) * 8;
            bf16x8 af[4], bfv[4];
#pragma unroll
            for (int i = 0; i < 4; i++)
                af[i] = *(bf16x8*)&As[(wm + i * 16 + lrow) * 64 + ch];
#pragma unroll
            for (int j = 0; j < 4; j++)
                bfv[j] = *(bf16x8*)&Bs[(wn + j * 16 + lrow) * 64 + ch];
#pragma unroll
            for (int i = 0; i < 4; i++)
#pragma unroll
                for (int j = 0; j < 4; j++)
                    acc[i][j] = __builtin_amdgcn_mfma_f32_16x16x32_bf16(af[i], bfv[j], acc[i][j], 0, 0, 0);
        }
    }

#pragma unroll
    for (int i = 0; i < 4; i++) {
#pragma unroll
        for (int g = 0; g < 4; g++) {
            const int m = m0 + wm + i * 16 + quad * 4 + g;
            if (m < cnt) {
                const int tok = perm_tok[seg0 + m];
                const float wgt = perm_w[seg0 + m];
                float* orow = out + (size_t)tok * DIM + n0 + wn + lrow;
#pragma unroll
                for (int j = 0; j < 4; j++)
                    atomicAdd(&orow[j * 16], acc[i][j][g] * wgt);
            }
        }
    }
}

extern "C" void kernel_launch(void* const* d_in, const int* in_sizes, int n_in,
                              void* d_out, int out_size, void* d_ws, size_t ws_size,
                              hipStream_t stream) {
    const float* x      = (const float*)d_in[0];
    const float* gate_w = (const float*)d_in[1];
    const float* w_fc   = (const float*)d_in[2];
    const float* w_proj = (const float*)d_in[3];
    float* out = (float*)d_out;

    if (ws_size < WS_NEEDED) return;

    char* w = (char*)d_ws;
    int*    counts    = (int*)(w + OFF_COUNTS);
    float*  probs_sum = (float*)(w + OFF_PSUM);
    int*    off_pad   = (int*)(w + OFF_OFFPAD);
    int*    cursor    = (int*)(w + OFF_CURSOR);
    int*    tok_e     = (int*)(w + OFF_TOKE);
    float*  tok_w     = (float*)(w + OFF_TOKW);
    int*    perm_tok  = (int*)(w + OFF_PERMT);
    float*  perm_w    = (float*)(w + OFF_PERMW);
    bf16_t* xp        = (bf16_t*)(w + OFF_XP);
    bf16_t* wfc_b     = (bf16_t*)(w + OFF_WFC);
    bf16_t* wpj_b     = (bf16_t*)(w + OFF_WPJ);
    bf16_t* hbuf      = (bf16_t*)(w + OFF_H);

    hipMemsetAsync(d_ws, 0, 256, stream);
    hipMemsetAsync(d_out, 0, (size_t)out_size * sizeof(float), stream);

    convert_w_kernel<<<9216, 256, 0, stream>>>(w_fc, w_proj, wfc_b, wpj_b);
    gate_kernel<<<N_TOK / 4, 256, 0, stream>>>(x, gate_w, counts, probs_sum, tok_e, tok_w);
    finalize_gate<<<1, 64, 0, stream>>>(counts, probs_sum, off_pad, cursor,
                                        out + (size_t)out_size - 1);
    scatter_kernel<<<(N_TOK + 255) / 256, 256, 0, stream>>>(tok_e, tok_w, cursor, perm_tok, perm_w);
    gather_x_kernel<<<PADROWS * DIM / 4 / 256, 256, 0, stream>>>(x, off_pad, counts, perm_tok, xp);

    // m-tiles = 32 so experts with up to 4096 tokens are fully covered.
    gemm1_kernel<<<dim3(32, HID / 128, NEXP), 256, 0, stream>>>(xp, wfc_b, off_pad, hbuf);
    gemm2_kernel<<<dim3(32, DIM / 128, NEXP * 4), 256, 0, stream>>>(hbuf, wpj_b, off_pad, counts,
                                                                    perm_tok, perm_w, out);
}

// Round 6
// 398.332 us; speedup vs baseline: 1.4865x; 1.4865x over previous
//
#include <hip/hip_runtime.h>
#include <hip/hip_bf16.h>

typedef __bf16 bf16_t;
typedef bf16_t bf16x8 __attribute__((ext_vector_type(8)));
typedef bf16_t bf16x4 __attribute__((ext_vector_type(4)));
typedef float f32x4 __attribute__((ext_vector_type(4)));

#define N_TOK 4096
#define DIM   768
#define HID   3072
#define NEXP  8
#define PADROWS 9216   // 8192 + 8*128 headroom for per-expert 128-padding
#define MMAX  32       // m-tiles per expert (covers worst-case 4096 tokens)

// ---------------- ws layout (bytes) ----------------
#define OFF_COUNTS 0
#define OFF_PSUM   32
#define OFF_OFFPAD 64      // int off_pad[9]
#define OFF_CURSOR 128
#define OFF_TOKE   256                         // int[8192]
#define OFF_TOKW   (OFF_TOKE + 4*8192)         // float[8192]
#define OFF_PERMT  (OFF_TOKW + 4*8192)         // int[PADROWS]
#define OFF_PERMW  (OFF_PERMT + 4*PADROWS)     // float[PADROWS]
#define OFF_XP     (((OFF_PERMW + 4*PADROWS) + 511) & ~511ull)  // bf16[PADROWS*DIM]
#define OFF_WFC    (OFF_XP + 2ull*PADROWS*DIM)                  // bf16[8*HID*DIM]
#define OFF_WPJ    (OFF_WFC + 2ull*NEXP*HID*DIM)                // bf16[8*DIM*HID]
#define OFF_H      (OFF_WPJ + 2ull*NEXP*DIM*HID)                // bf16[PADROWS*HID]
#define WS_NEEDED  (OFF_H + 2ull*PADROWS*HID)

// ---------------- async global->LDS 16B ----------------
__device__ __forceinline__ void async_copy16(const bf16_t* g, bf16_t* l) {
    __builtin_amdgcn_global_load_lds(
        (const __attribute__((address_space(1))) void*)g,
        (__attribute__((address_space(3))) void*)l, 16, 0, 0);
}

// ---------------- gating: one wave per token ----------------
__global__ __launch_bounds__(256) void gate_kernel(
    const float* __restrict__ x, const float* __restrict__ gw,
    int* __restrict__ counts, float* __restrict__ probs_sum,
    int* __restrict__ tok_e, float* __restrict__ tok_w)
{
    __shared__ float ps[8];
    __shared__ int cs[8];
    if (threadIdx.x < 8) { ps[threadIdx.x] = 0.f; cs[threadIdx.x] = 0; }
    __syncthreads();

    const int wv = threadIdx.x >> 6, lane = threadIdx.x & 63;
    const int n = blockIdx.x * 4 + wv;

    float acc[8];
#pragma unroll
    for (int e = 0; e < 8; e++) acc[e] = 0.f;
    const float* xr = x + (size_t)n * DIM;
#pragma unroll
    for (int c = 0; c < 12; c++) {
        const float xv = xr[c * 64 + lane];
#pragma unroll
        for (int e = 0; e < 8; e++) acc[e] += xv * gw[e * DIM + c * 64 + lane];
    }
#pragma unroll
    for (int e = 0; e < 8; e++)
        for (int off = 32; off > 0; off >>= 1) acc[e] += __shfl_xor(acc[e], off, 64);

    float mx = acc[0];
#pragma unroll
    for (int e = 1; e < 8; e++) mx = fmaxf(mx, acc[e]);
    float p[8], s = 0.f;
#pragma unroll
    for (int e = 0; e < 8; e++) { p[e] = expf(acc[e] - mx); s += p[e]; }

    int e1 = 0;
#pragma unroll
    for (int e = 1; e < 8; e++) if (p[e] > p[e1]) e1 = e;
    int e2 = (e1 == 0) ? 1 : 0;
#pragma unroll
    for (int e = 0; e < 8; e++) if (e != e1 && p[e] > p[e2]) e2 = e;
    const float denom = p[e1] + p[e2];

    if (lane == 0) {
        tok_e[2 * n] = e1; tok_e[2 * n + 1] = e2;
        tok_w[2 * n] = p[e1] / denom; tok_w[2 * n + 1] = p[e2] / denom;
        const float inv = 1.f / s;
#pragma unroll
        for (int e = 0; e < 8; e++) atomicAdd(&ps[e], p[e] * inv);
        atomicAdd(&cs[e1], 1); atomicAdd(&cs[e2], 1);
    }
    __syncthreads();
    if (threadIdx.x < 8) {
        atomicAdd(&probs_sum[threadIdx.x], ps[threadIdx.x]);
        atomicAdd(&counts[threadIdx.x], cs[threadIdx.x]);
    }
}

// ---------------- finalize: padded offsets + balance loss ----------------
__global__ void finalize_gate(const int* __restrict__ counts,
                              const float* __restrict__ probs_sum,
                              int* __restrict__ off_pad, int* __restrict__ cursor,
                              float* __restrict__ out_loss)
{
    if (threadIdx.x == 0) {
        int off = 0;
        for (int e = 0; e < 8; e++) {
            off_pad[e] = off; cursor[e] = off;
            off += ((counts[e] + 127) & ~127);
        }
        off_pad[8] = off;
        float loss = 0.f;
        for (int e = 0; e < 8; e++) loss += probs_sum[e] * (float)counts[e];
        loss *= 8.f / ((float)N_TOK * (float)N_TOK);
        *out_loss = loss;
    }
}

// ---------------- scatter tokens into padded per-expert segments ----------------
__global__ __launch_bounds__(256) void scatter_kernel(
    const int* __restrict__ tok_e, const float* __restrict__ tok_w,
    int* __restrict__ cursor, int* __restrict__ perm_tok, float* __restrict__ perm_w)
{
    const int n = blockIdx.x * 256 + threadIdx.x;
    if (n < N_TOK) {
#pragma unroll
        for (int k = 0; k < 2; k++) {
            const int e = tok_e[2 * n + k];
            const int pos = atomicAdd(&cursor[e], 1);
            perm_tok[pos] = n;
            perm_w[pos] = tok_w[2 * n + k];
        }
    }
}

// ---------------- convert both weight tensors fp32 -> bf16 ----------------
__global__ __launch_bounds__(256) void convert_w_kernel(
    const float* __restrict__ w_fc, const float* __restrict__ w_proj,
    bf16_t* __restrict__ wfc_b, bf16_t* __restrict__ wpj_b)
{
    const long long half = 18874368LL;  // 8*3072*768
    long long base = ((long long)blockIdx.x * 256 + threadIdx.x) * 16;
    const float* src; bf16_t* dst;
    if (base < half) { src = w_fc + base; dst = wfc_b + base; }
    else             { src = w_proj + (base - half); dst = wpj_b + (base - half); }
    float v[16];
    *(float4*)&v[0]  = *(const float4*)(src);
    *(float4*)&v[4]  = *(const float4*)(src + 4);
    *(float4*)&v[8]  = *(const float4*)(src + 8);
    *(float4*)&v[12] = *(const float4*)(src + 12);
    bf16x8 lo, hi;
#pragma unroll
    for (int i = 0; i < 8; i++) { lo[i] = (bf16_t)v[i]; hi[i] = (bf16_t)v[8 + i]; }
    *(bf16x8*)dst       = lo;
    *(bf16x8*)(dst + 8) = hi;
}

// ---------------- gather permuted tokens, fp32 -> bf16, zero pad rows ----------------
__global__ __launch_bounds__(256) void gather_x_kernel(
    const float* __restrict__ x, const int* __restrict__ off_pad,
    const int* __restrict__ counts, const int* __restrict__ perm_tok,
    bf16_t* __restrict__ xp)
{
    __shared__ int so[9], scnt[8];
    if (threadIdx.x < 9) so[threadIdx.x] = off_pad[threadIdx.x];
    if (threadIdx.x < 8) scnt[threadIdx.x] = counts[threadIdx.x];
    __syncthreads();
    const int gid = blockIdx.x * 256 + threadIdx.x;
    const int p = gid / 192;            // padded row
    const int c = (gid - p * 192) * 4;  // column
    int e = 0;
#pragma unroll
    for (int k = 1; k < 8; k++) if (p >= so[k]) e = k;
    const bool valid = (p < so[8]) && (p - so[e] < scnt[e]);
    float4 v = make_float4(0.f, 0.f, 0.f, 0.f);
    if (valid) {
        const int tok = perm_tok[p];
        v = *(const float4*)(x + (size_t)tok * DIM + c);
    }
    bf16x4 o; o[0] = (bf16_t)v.x; o[1] = (bf16_t)v.y; o[2] = (bf16_t)v.z; o[3] = (bf16_t)v.w;
    *(bf16x4*)(xp + (size_t)p * DIM + c) = o;
}

// ---------------- GEMM1: h = relu(xp @ w_fc^T)^2 ----------------
// 128x128 tile, BK=64, XOR-swizzled LDS, single-buffer K-loop (R3 structure).
// 1D grid, XCD-locality decompose: id = xcd + 8*slot, xcd = expert,
// slot = n_t*MMAX + m_t  (B-tile pinned, A sweeps; both fit per-XCD L2).
__global__ __launch_bounds__(256, 2) void gemm1_kernel(
    const bf16_t* __restrict__ xp, const bf16_t* __restrict__ wfc,
    const int* __restrict__ off_pad, bf16_t* __restrict__ h)
{
    const int id = blockIdx.x;
    const int e = id & 7;
    const int slot = id >> 3;
    const int n_t = slot / MMAX, m_t = slot % MMAX;

    const int seg0 = off_pad[e];
    const int cnt_pad = off_pad[e + 1] - seg0;
    const int m0 = m_t * 128;
    if (m0 >= cnt_pad) return;
    const int n0 = n_t * 128;  // over HID

    __shared__ bf16_t As[128 * 64];
    __shared__ bf16_t Bs[128 * 64];

    const int t = threadIdx.x;
    const int srow = t >> 3, sc = t & 7;
    const int gsc = sc ^ (srow & 7);   // swizzled global chunk -> linear LDS slot
    const bf16_t* abase = xp + (size_t)(seg0 + m0 + srow) * DIM + gsc * 8;
    const bf16_t* bbase = wfc + ((size_t)e * HID + n0 + srow) * DIM + gsc * 8;

    const int wv = t >> 6, lane = t & 63;
    const int lrow = lane & 15, quad = lane >> 4;
    const int wm = (wv & 1) * 64, wn = (wv >> 1) * 64;
    const int sw = lrow & 7;           // read-side swizzle key

    f32x4 acc[4][4] = {};

    for (int k0 = 0; k0 < DIM; k0 += 64) {
        __syncthreads();
#pragma unroll
        for (int ii = 0; ii < 4; ii++) {
            async_copy16(abase + (size_t)ii * 32 * DIM + k0, &As[(ii * 256 + t) * 8]);
            async_copy16(bbase + (size_t)ii * 32 * DIM + k0, &Bs[(ii * 256 + t) * 8]);
        }
        __syncthreads();
#pragma unroll
        for (int kh = 0; kh < 2; kh++) {
            const int ch = ((kh * 4 + quad) ^ sw) * 8;
            bf16x8 af[4], bfv[4];
#pragma unroll
            for (int i = 0; i < 4; i++)
                af[i] = *(bf16x8*)&As[(wm + i * 16 + lrow) * 64 + ch];
#pragma unroll
            for (int j = 0; j < 4; j++)
                bfv[j] = *(bf16x8*)&Bs[(wn + j * 16 + lrow) * 64 + ch];
#pragma unroll
            for (int i = 0; i < 4; i++)
#pragma unroll
                for (int j = 0; j < 4; j++)
                    acc[i][j] = __builtin_amdgcn_mfma_f32_16x16x32_bf16(af[i], bfv[j], acc[i][j], 0, 0, 0);
        }
    }

    // epilogue: relu^2 -> bf16. C/D map: col=lane&15 (n), row=quad*4+reg (m).
#pragma unroll
    for (int i = 0; i < 4; i++) {
#pragma unroll
        for (int g = 0; g < 4; g++) {
            const int m = m0 + wm + i * 16 + quad * 4 + g;
            bf16_t* hrow = h + (size_t)(seg0 + m) * HID + n0 + wn + lrow;
#pragma unroll
            for (int j = 0; j < 4; j++) {
                float v = fmaxf(acc[i][j][g], 0.f);
                hrow[j * 16] = (bf16_t)(v * v);
            }
        }
    }
}

// ---------------- GEMM2: out[tok] += w * (h @ w_proj^T), split-K=2, atomics ----------------
// 1D grid, XCD-locality decompose: xcd = expert,
// slot = split*(MMAX*6) + m_t*6 + n_t  (6 n-blocks share each A-tile; B-half resident).
__global__ __launch_bounds__(256, 2) void gemm2_kernel(
    const bf16_t* __restrict__ h, const bf16_t* __restrict__ wpj,
    const int* __restrict__ off_pad, const int* __restrict__ counts,
    const int* __restrict__ perm_tok, const float* __restrict__ perm_w,
    float* __restrict__ out)
{
    const int id = blockIdx.x;
    const int e = id & 7;
    const int slot = id >> 3;
    const int split = slot / (MMAX * 6);
    const int rem = slot % (MMAX * 6);
    const int m_t = rem / 6, n_t = rem % 6;

    const int seg0 = off_pad[e];
    const int cnt = counts[e];
    const int m0 = m_t * 128;
    if (m0 >= cnt) return;
    const int n0 = n_t * 128;  // over DIM
    const int kbeg = split * (HID / 2);

    __shared__ bf16_t As[128 * 64];
    __shared__ bf16_t Bs[128 * 64];

    const int t = threadIdx.x;
    const int srow = t >> 3, sc = t & 7;
    const int gsc = sc ^ (srow & 7);
    const bf16_t* abase = h + (size_t)(seg0 + m0 + srow) * HID + kbeg + gsc * 8;
    const bf16_t* bbase = wpj + ((size_t)e * DIM + n0 + srow) * HID + kbeg + gsc * 8;

    const int wv = t >> 6, lane = t & 63;
    const int lrow = lane & 15, quad = lane >> 4;
    const int wm = (wv & 1) * 64, wn = (wv >> 1) * 64;
    const int sw = lrow & 7;

    f32x4 acc[4][4] = {};

    for (int k0 = 0; k0 < HID / 2; k0 += 64) {
        __syncthreads();
#pragma unroll
        for (int ii = 0; ii < 4; ii++) {
            async_copy16(abase + (size_t)ii * 32 * HID + k0, &As[(ii * 256 + t) * 8]);
            async_copy16(bbase + (size_t)ii * 32 * HID + k0, &Bs[(ii * 256 + t) * 8]);
        }
        __syncthreads();
#pragma unroll
        for (int kh = 0; kh < 2; kh++) {
            const int ch = ((kh * 4 + quad) ^ sw) * 8;
            bf16x8 af[4], bfv[4];
#pragma unroll
            for (int i = 0; i < 4; i++)
                af[i] = *(bf16x8*)&As[(wm + i * 16 + lrow) * 64 + ch];
#pragma unroll
            for (int j = 0; j < 4; j++)
                bfv[j] = *(bf16x8*)&Bs[(wn + j * 16 + lrow) * 64 + ch];
#pragma unroll
            for (int i = 0; i < 4; i++)
#pragma unroll
                for (int j = 0; j < 4; j++)
                    acc[i][j] = __builtin_amdgcn_mfma_f32_16x16x32_bf16(af[i], bfv[j], acc[i][j], 0, 0, 0);
        }
    }

#pragma unroll
    for (int i = 0; i < 4; i++) {
#pragma unroll
        for (int g = 0; g < 4; g++) {
            const int m = m0 + wm + i * 16 + quad * 4 + g;
            if (m < cnt) {
                const int tok = perm_tok[seg0 + m];
                const float wgt = perm_w[seg0 + m];
                float* orow = out + (size_t)tok * DIM + n0 + wn + lrow;
#pragma unroll
                for (int j = 0; j < 4; j++)
                    atomicAdd(&orow[j * 16], acc[i][j][g] * wgt);
            }
        }
    }
}

extern "C" void kernel_launch(void* const* d_in, const int* in_sizes, int n_in,
                              void* d_out, int out_size, void* d_ws, size_t ws_size,
                              hipStream_t stream) {
    const float* x      = (const float*)d_in[0];
    const float* gate_w = (const float*)d_in[1];
    const float* w_fc   = (const float*)d_in[2];
    const float* w_proj = (const float*)d_in[3];
    float* out = (float*)d_out;

    if (ws_size < WS_NEEDED) return;

    char* w = (char*)d_ws;
    int*    counts    = (int*)(w + OFF_COUNTS);
    float*  probs_sum = (float*)(w + OFF_PSUM);
    int*    off_pad   = (int*)(w + OFF_OFFPAD);
    int*    cursor    = (int*)(w + OFF_CURSOR);
    int*    tok_e     = (int*)(w + OFF_TOKE);
    float*  tok_w     = (float*)(w + OFF_TOKW);
    int*    perm_tok  = (int*)(w + OFF_PERMT);
    float*  perm_w    = (float*)(w + OFF_PERMW);
    bf16_t* xp        = (bf16_t*)(w + OFF_XP);
    bf16_t* wfc_b     = (bf16_t*)(w + OFF_WFC);
    bf16_t* wpj_b     = (bf16_t*)(w + OFF_WPJ);
    bf16_t* hbuf      = (bf16_t*)(w + OFF_H);

    hipMemsetAsync(d_ws, 0, 256, stream);
    hipMemsetAsync(d_out, 0, (size_t)out_size * sizeof(float), stream);

    convert_w_kernel<<<9216, 256, 0, stream>>>(w_fc, w_proj, wfc_b, wpj_b);
    gate_kernel<<<N_TOK / 4, 256, 0, stream>>>(x, gate_w, counts, probs_sum, tok_e, tok_w);
    finalize_gate<<<1, 64, 0, stream>>>(counts, probs_sum, off_pad, cursor,
                                        out + (size_t)out_size - 1);
    scatter_kernel<<<(N_TOK + 255) / 256, 256, 0, stream>>>(tok_e, tok_w, cursor, perm_tok, perm_w);
    gather_x_kernel<<<PADROWS * DIM / 4 / 256, 256, 0, stream>>>(x, off_pad, counts, perm_tok, xp);

    // XCD-locality 1D grids: id = xcd + 8*slot (xcd = expert).
    gemm1_kernel<<<8 * 24 * MMAX, 256, 0, stream>>>(xp, wfc_b, off_pad, hbuf);
    gemm2_kernel<<<8 * 2 * MMAX * 6, 256, 0, stream>>>(hbuf, wpj_b, off_pad, counts,
                                                       perm_tok, perm_w, out);
}